// Round 6
// baseline (74.362 us; speedup 1.0000x reference)
//
#include <hip/hip_runtime.h>

#define T_LEN  1048576
#define NROWS  32
#define NTAPS  128
#define N2     32
#define BLOCK  256
#define SEG    4096           /* outputs per block */
#define SEGS_PER_ROW 256
#define HALO   256            /* staged gi = n0 - HALO + e  (16B-aligned DMA) */
#define NCH    11             /* K chunks of 16: k = m + 129 - 16c - s */
#define STG_CH 1088           /* staged 16B chunks = (SEG+HALO)/4 */

typedef __attribute__((ext_vector_type(8)))  _Float16 half8;
typedef __attribute__((ext_vector_type(2)))  __fp16   fp16x2;
typedef __attribute__((ext_vector_type(16))) float    f32x16;

__device__ __forceinline__ int swz(int q) { return q ^ ((q >> 3) & 7); }

__device__ __forceinline__ void gload_lds16(const float* g, float* l) {
  __builtin_amdgcn_global_load_lds(
      (const __attribute__((address_space(1))) void*)g,
      (__attribute__((address_space(3))) void*)l, 16, 0, 0);
}

// ---- kernel 1: impulse response h[0..127] (+D at 0); fp16 Toeplitz A-frags ----
// A_c[m,s] = h[m + 129 - 16c - s], lane=(m=lane&31, g=lane>>5), s=8g+i
__global__ __launch_bounds__(NTAPS) void ssm_taps(
    const float* __restrict__ w_real, const float* __restrict__ w_imag,
    const float* __restrict__ log_dt,
    const float* __restrict__ C_real, const float* __restrict__ C_imag,
    const float* __restrict__ B_real, const float* __restrict__ B_imag,
    const float* __restrict__ Dp, float* __restrict__ ws) {
  __shared__ float hsh[NTAPS];
  const int k = threadIdx.x;                 // 0..127
  const float dt = expf(log_dt[0]);
  const float kf = (float)k;
  float acc = 0.f;
  for (int n = 0; n < N2; ++n) {
    const float a  = dt * w_real[n];
    const float b  = dt * w_imag[n];
    const float cr = C_real[n], ci = C_imag[n];
    const float br = B_real[n], bi = B_imag[n];
    const float coef_r = cr * br - ci * bi;
    const float coef_i = cr * bi + ci * br;
    const float e = expf(a * kf);
    float s, c;
    sincosf(b * kf, &s, &c);
    acc += e * (coef_r * c - coef_i * s);
  }
  if (k == 0) acc += Dp[0];
  ws[k]  = acc;                              // plain h (fix kernel)
  hsh[k] = acc;
  __syncthreads();
  if (k < 64) {
    _Float16* AH = (_Float16*)(ws + NTAPS);
    const int m = k & 31, g = k >> 5;
    for (int c = 0; c < NCH; ++c)
      for (int i = 0; i < 8; ++i) {
        const int idx = m + 129 - 16 * c - 8 * g - i;
        const float v = (idx >= 0 && idx < NTAPS) ? hsh[idx] : 0.f;
        AH[(c * 64 + k) * 8 + i] = (_Float16)v;   // RNE
      }
  }
}

// ---- kernel 2: implicit-GEMM FIR; 1 segment/block, full-TLP latency hiding ----
__global__ __launch_bounds__(BLOCK, 8) void ssm_conv(
    const float* __restrict__ x, const float* __restrict__ ws,
    float* __restrict__ out) {
  __shared__ __align__(16) float lds[STG_CH * 4];      // 17408 B

  const int tid  = threadIdx.x;
  const int lane = tid & 63;
  const int wid  = tid >> 6;
  const int p    = lane & 31, g = lane >> 5;
  const int row  = blockIdx.x >> 8;          // 256 blocks per row
  const int jb   = blockIdx.x & 255;
  const int n0   = jb * SEG;
  const float* __restrict__ xrow = x + (size_t)row * T_LEN;
  const half8* __restrict__ wsA = (const half8*)(ws + NTAPS);

  // stage segment: linear LDS dest (DMA), sigma-permuted global source
#pragma unroll
  for (int j = 0; j < 5; ++j) {
    const int ch = j * 256 + wid * 64 + lane;
    if (ch < STG_CH) {
      int gfi = n0 - HALO + 4 * swz(ch);     // 16B-aligned; clamp left edge
      gfi = gfi < 0 ? 0 : gfi;
      gload_lds16(xrow + gfi, &lds[(j * 256 + wid * 64) * 4]);
    }
  }
  asm volatile("s_waitcnt vmcnt(0)" ::: "memory");
  __syncthreads();

  f32x16 acc = {};
#pragma unroll
  for (int c = 0; c < NCH; ++c) {
    const half8 A = wsA[c * 64 + lane];      // L1-hot after first wave
    const int q0 = wid * 256 + 8 * p + 2 * g + 4 * c;   // 16B chunk idx (even)
    const float4 f0 = *(const float4*)(lds + (swz(q0) << 2));
    const float4 f1 = *(const float4*)(lds + (swz(q0 + 1) << 2));
    union { half8 h8; unsigned u[4]; } bu;
    bu.u[0] = __builtin_bit_cast(unsigned, __builtin_amdgcn_cvt_pkrtz(f0.x, f0.y));
    bu.u[1] = __builtin_bit_cast(unsigned, __builtin_amdgcn_cvt_pkrtz(f0.z, f0.w));
    bu.u[2] = __builtin_bit_cast(unsigned, __builtin_amdgcn_cvt_pkrtz(f1.x, f1.y));
    bu.u[3] = __builtin_bit_cast(unsigned, __builtin_amdgcn_cvt_pkrtz(f1.z, f1.w));
    acc = __builtin_amdgcn_mfma_f32_32x32x16_f16(A, bu.h8, acc, 0, 0, 0);
  }

  // C/D map: col=p, row m=(r&3)+8*(r>>2)+4g -> reg-quads are m-contiguous
  float* __restrict__ orow =
      out + (size_t)row * T_LEN + n0 + wid * 1024 + 32 * p + 4 * g;
#pragma unroll
  for (int kq = 0; kq < 4; ++kq) {
    float4 v;
    v.x = acc[4 * kq];     v.y = acc[4 * kq + 1];
    v.z = acc[4 * kq + 2]; v.w = acc[4 * kq + 3];
    *(float4*)(orow + 8 * kq) = v;
  }
}

// ---- kernel 3: exact fp32 fixup for n in [0,254) (wraparound + left edge) ----
__global__ __launch_bounds__(BLOCK) void ssm_fix(
    const float* __restrict__ x, const float* __restrict__ ws,
    float* __restrict__ out) {
  const int row = blockIdx.x;
  const int n = threadIdx.x;
  const float* __restrict__ h = ws;
  const float* __restrict__ xrow = x + (size_t)row * T_LEN;
  float acc = 0.f;
  if (n < 127) {                             // circular wraparound region
    for (int k = n + 1; k < NTAPS; ++k)
      acc += h[k] * xrow[T_LEN + n - k];
  } else if (n < 254) {                      // causal with zero left-pad
    for (int k = 0; k <= n - 127; ++k)
      acc += h[k] * xrow[n - 127 - k];
  } else {
    return;
  }
  out[(size_t)row * T_LEN + n] = acc;
}

extern "C" void kernel_launch(void* const* d_in, const int* in_sizes, int n_in,
                              void* d_out, int out_size, void* d_ws, size_t ws_size,
                              hipStream_t stream) {
  const float* x      = (const float*)d_in[0];
  const float* w_real = (const float*)d_in[1];
  const float* w_imag = (const float*)d_in[2];
  const float* log_dt = (const float*)d_in[3];
  const float* C_real = (const float*)d_in[4];
  const float* C_imag = (const float*)d_in[5];
  const float* B_real = (const float*)d_in[6];
  const float* B_imag = (const float*)d_in[7];
  const float* Dp     = (const float*)d_in[8];
  float* out = (float*)d_out;
  float* ws  = (float*)d_ws;   // 128 f32 h + NCH*64*8 fp16 A-frags = 11.8 KB

  ssm_taps<<<1, NTAPS, 0, stream>>>(w_real, w_imag, log_dt,
                                    C_real, C_imag, B_real, B_imag, Dp, ws);
  ssm_conv<<<NROWS * SEGS_PER_ROW, BLOCK, 0, stream>>>(x, ws, out);
  ssm_fix<<<NROWS, BLOCK, 0, stream>>>(x, ws, out);
}

// Round 7
// 71.374 us; speedup vs baseline: 1.0419x; 1.0419x over previous
//
#include <hip/hip_runtime.h>

#define T_LEN  1048576
#define NROWS  32
#define NTAPS  128
#define N2     32
#define BLOCK  256
#define SEG    4096           /* outputs per block */
#define SEGS_PER_ROW 256
#define HALO   256            /* staged gi = n0 - HALO + e  (16B-aligned DMA) */
#define NCH    11             /* K chunks of 16: k = m + 129 - 16c - s */
#define STG_CH 1088           /* staged 16B chunks = (SEG+HALO)/4 */

typedef __attribute__((ext_vector_type(8)))  _Float16 half8;
typedef __attribute__((ext_vector_type(2)))  __fp16   fp16x2;
typedef __attribute__((ext_vector_type(16))) float    f32x16;

__device__ __forceinline__ int swz(int q) { return q ^ ((q >> 3) & 7); }

__device__ __forceinline__ void gload_lds16(const void* g, void* l) {
  __builtin_amdgcn_global_load_lds(
      (const __attribute__((address_space(1))) void*)g,
      (__attribute__((address_space(3))) void*)l, 16, 0, 0);
}

// ---- kernel 1: impulse response h[0..127] (+D at 0); fp16 Toeplitz A-frags ----
// A_c[m,s] = h[m + 129 - 16c - s], lane=(m=lane&31, g=lane>>5), s=8g+i
__global__ __launch_bounds__(NTAPS) void ssm_taps(
    const float* __restrict__ w_real, const float* __restrict__ w_imag,
    const float* __restrict__ log_dt,
    const float* __restrict__ C_real, const float* __restrict__ C_imag,
    const float* __restrict__ B_real, const float* __restrict__ B_imag,
    const float* __restrict__ Dp, float* __restrict__ ws) {
  __shared__ float hsh[NTAPS];
  const int k = threadIdx.x;                 // 0..127
  const float dt = expf(log_dt[0]);
  const float kf = (float)k;
  float acc = 0.f;
  for (int n = 0; n < N2; ++n) {
    const float a  = dt * w_real[n];
    const float b  = dt * w_imag[n];
    const float cr = C_real[n], ci = C_imag[n];
    const float br = B_real[n], bi = B_imag[n];
    const float coef_r = cr * br - ci * bi;
    const float coef_i = cr * bi + ci * br;
    const float e = expf(a * kf);
    float s, c;
    sincosf(b * kf, &s, &c);
    acc += e * (coef_r * c - coef_i * s);
  }
  if (k == 0) acc += Dp[0];
  ws[k]  = acc;                              // plain h (fix kernel)
  hsh[k] = acc;
  __syncthreads();
  if (k < 64) {
    _Float16* AH = (_Float16*)(ws + NTAPS);
    const int m = k & 31, g = k >> 5;
    for (int c = 0; c < NCH; ++c)
      for (int i = 0; i < 8; ++i) {
        const int idx = m + 129 - 16 * c - 8 * g - i;
        const float v = (idx >= 0 && idx < NTAPS) ? hsh[idx] : 0.f;
        AH[(c * 64 + k) * 8 + i] = (_Float16)v;   // RNE
      }
  }
}

// ---- kernel 2: implicit-GEMM FIR; DMA-staged x + A in LDS, transposed
//                coalesced epilogue through the (dead) x buffer ----
__global__ __launch_bounds__(BLOCK, 4) void ssm_conv(
    const float* __restrict__ x, const float* __restrict__ ws,
    float* __restrict__ out) {
  __shared__ __align__(16) unsigned char smem[28672];  // 17408 x + 11264 A
  float*    xs   = (float*)smem;
  _Float16* ldsA = (_Float16*)(smem + 17408);

  const int tid  = threadIdx.x;
  const int lane = tid & 63;
  const int wid  = tid >> 6;
  const int p    = lane & 31, g = lane >> 5;
  const int row  = blockIdx.x >> 8;          // 256 blocks per row
  const int jb   = blockIdx.x & 255;
  const int n0   = jb * SEG;
  const float* __restrict__ xrow = x + (size_t)row * T_LEN;

  // stage x: linear LDS dest (DMA), sigma-permuted global source (involution)
#pragma unroll
  for (int j = 0; j < 5; ++j) {
    const int ch = j * 256 + wid * 64 + lane;
    if (ch < STG_CH) {
      int gfi = n0 - HALO + 4 * swz(ch);     // 16B-aligned; clamp left edge
      gfi = gfi < 0 ? 0 : gfi;
      gload_lds16(xrow + gfi, xs + (j * 256 + wid * 64) * 4);
    }
  }
  // stage A-frags (11 KB, wave 0 only) concurrently with x-DMA
  if (wid == 0) {
    const _Float16* gA = (const _Float16*)(ws + NTAPS);
#pragma unroll
    for (int c = 0; c < NCH; ++c)
      gload_lds16(gA + (c * 64 + lane) * 8, ldsA + c * 512);
  }
  asm volatile("s_waitcnt vmcnt(0)" ::: "memory");
  __syncthreads();

  f32x16 acc = {};
#pragma unroll
  for (int c = 0; c < NCH; ++c) {
    const half8 A = *(const half8*)(ldsA + c * 512 + lane * 8);
    const int q0 = wid * 256 + 8 * p + 2 * g + 4 * c;   // 16B chunk idx (even)
    const float4 f0 = *(const float4*)(xs + (swz(q0) << 2));
    const float4 f1 = *(const float4*)(xs + (swz(q0 + 1) << 2));
    union { half8 h8; unsigned u[4]; } bu;
    bu.u[0] = __builtin_bit_cast(unsigned, __builtin_amdgcn_cvt_pkrtz(f0.x, f0.y));
    bu.u[1] = __builtin_bit_cast(unsigned, __builtin_amdgcn_cvt_pkrtz(f0.z, f0.w));
    bu.u[2] = __builtin_bit_cast(unsigned, __builtin_amdgcn_cvt_pkrtz(f1.x, f1.y));
    bu.u[3] = __builtin_bit_cast(unsigned, __builtin_amdgcn_cvt_pkrtz(f1.z, f1.w));
    acc = __builtin_amdgcn_mfma_f32_32x32x16_f16(A, bu.h8, acc, 0, 0, 0);
  }

  // epilogue: transpose through LDS (reuse x buffer), then coalesced stores.
  // wave-private region [wid*1056, +1056): offset(m,p) = m*33 + p
  __syncthreads();                           // all x-reads done before overwrite
  float* ebuf = (float*)smem;
  const int wr = wid * 1056;
#pragma unroll
  for (int r = 0; r < 16; ++r) {
    const int m = (r & 3) + 8 * (r >> 2) + 4 * g;   // C/D row map; col = p
    ebuf[wr + m * 33 + p] = acc[r];
  }
  float* __restrict__ obase = out + (size_t)row * T_LEN + n0 + wid * 1024;
#pragma unroll
  for (int pp = 0; pp < 4; ++pp) {
    const int o  = 4 * lane + 256 * pp;      // outputs o..o+3 of this wave
    const int m0 = o & 31, pc = o >> 5;      // o = 32*pc + m
    float4 v;
    v.x = ebuf[wr + (m0 + 0) * 33 + pc];
    v.y = ebuf[wr + (m0 + 1) * 33 + pc];
    v.z = ebuf[wr + (m0 + 2) * 33 + pc];
    v.w = ebuf[wr + (m0 + 3) * 33 + pc];
    *(float4*)(obase + o) = v;               // 64 lanes x 16B contiguous
  }
}

// ---- kernel 3: exact fp32 fixup for n in [0,254) (wraparound + left edge) ----
__global__ __launch_bounds__(BLOCK) void ssm_fix(
    const float* __restrict__ x, const float* __restrict__ ws,
    float* __restrict__ out) {
  const int row = blockIdx.x;
  const int n = threadIdx.x;
  const float* __restrict__ h = ws;
  const float* __restrict__ xrow = x + (size_t)row * T_LEN;
  float acc = 0.f;
  if (n < 127) {                             // circular wraparound region
    for (int k = n + 1; k < NTAPS; ++k)
      acc += h[k] * xrow[T_LEN + n - k];
  } else if (n < 254) {                      // causal with zero left-pad
    for (int k = 0; k <= n - 127; ++k)
      acc += h[k] * xrow[n - 127 - k];
  } else {
    return;
  }
  out[(size_t)row * T_LEN + n] = acc;
}

extern "C" void kernel_launch(void* const* d_in, const int* in_sizes, int n_in,
                              void* d_out, int out_size, void* d_ws, size_t ws_size,
                              hipStream_t stream) {
  const float* x      = (const float*)d_in[0];
  const float* w_real = (const float*)d_in[1];
  const float* w_imag = (const float*)d_in[2];
  const float* log_dt = (const float*)d_in[3];
  const float* C_real = (const float*)d_in[4];
  const float* C_imag = (const float*)d_in[5];
  const float* B_real = (const float*)d_in[6];
  const float* B_imag = (const float*)d_in[7];
  const float* Dp     = (const float*)d_in[8];
  float* out = (float*)d_out;
  float* ws  = (float*)d_ws;   // 128 f32 h + NCH*64*8 fp16 A-frags = 11.8 KB

  ssm_taps<<<1, NTAPS, 0, stream>>>(w_real, w_imag, log_dt,
                                    C_real, C_imag, B_real, B_imag, Dp, ws);
  ssm_conv<<<NROWS * SEGS_PER_ROW, BLOCK, 0, stream>>>(x, ws, out);
  ssm_fix<<<NROWS, BLOCK, 0, stream>>>(x, ws, out);
}

// Round 8
// 65.748 us; speedup vs baseline: 1.1310x; 1.0856x over previous
//
#include <hip/hip_runtime.h>

#define T_LEN  1048576
#define NROWS  32
#define NTAPS  128
#define N2     32
#define BLOCK  256
#define SEG    4096           /* outputs per block */
#define SEGS_PER_ROW 256
#define HALO   256            /* staged element e <-> x[n0 - HALO + e] */
#define NCH    11             /* K chunks of 16: k = m + 129 - 16c - s */
#define STG_F32 (SEG + HALO)  /* 4352 staged elements */
#define STG_Q4  (STG_F32 / 4) /* 1088 float4 loads */
#define EPI_F32 (32 * 36)     /* per-wave epilogue region, pad 36 */

typedef __attribute__((ext_vector_type(8)))  _Float16 half8;
typedef __attribute__((ext_vector_type(2)))  __fp16   fp16x2;
typedef __attribute__((ext_vector_type(16))) float    f32x16;

__device__ __forceinline__ int swz16(int q) { return q ^ ((q >> 3) & 7); }

// ---- kernel 1: impulse response h[0..127] (+D at 0); fp16 Toeplitz A-frags ----
// A_c[m,s] = h[m + 129 - 16c - s], lane=(m=lane&31, g=lane>>5), s=8g+i
__global__ __launch_bounds__(NTAPS) void ssm_taps(
    const float* __restrict__ w_real, const float* __restrict__ w_imag,
    const float* __restrict__ log_dt,
    const float* __restrict__ C_real, const float* __restrict__ C_imag,
    const float* __restrict__ B_real, const float* __restrict__ B_imag,
    const float* __restrict__ Dp, float* __restrict__ ws) {
  __shared__ float hsh[NTAPS];
  const int k = threadIdx.x;                 // 0..127
  const float dt = expf(log_dt[0]);
  const float kf = (float)k;
  float acc = 0.f;
  for (int n = 0; n < N2; ++n) {
    const float a  = dt * w_real[n];
    const float b  = dt * w_imag[n];
    const float cr = C_real[n], ci = C_imag[n];
    const float br = B_real[n], bi = B_imag[n];
    const float coef_r = cr * br - ci * bi;
    const float coef_i = cr * bi + ci * br;
    const float e = expf(a * kf);
    float s, c;
    sincosf(b * kf, &s, &c);
    acc += e * (coef_r * c - coef_i * s);
  }
  if (k == 0) acc += Dp[0];
  ws[k]  = acc;                              // plain h (exact tail)
  hsh[k] = acc;
  __syncthreads();
  if (k < 64) {
    _Float16* AH = (_Float16*)(ws + NTAPS);
    const int m = k & 31, g = k >> 5;
    for (int c = 0; c < NCH; ++c)
      for (int i = 0; i < 8; ++i) {
        const int idx = m + 129 - 16 * c - 8 * g - i;
        const float v = (idx >= 0 && idx < NTAPS) ? hsh[idx] : 0.f;
        AH[(c * 64 + k) * 8 + i] = (_Float16)v;   // RNE
      }
  }
}

// ---- kernel 2: implicit-GEMM FIR; fp16 LDS staging, A in VGPRs,
//                vector transpose epilogue, merged exact edge tail ----
__global__ __launch_bounds__(BLOCK, 5) void ssm_conv(
    const float* __restrict__ x, const float* __restrict__ ws,
    float* __restrict__ out) {
  __shared__ __align__(16) unsigned char smem[4 * EPI_F32 * 4];  // 18432 B

  const int tid  = threadIdx.x;
  const int lane = tid & 63;
  const int wid  = tid >> 6;
  const int p    = lane & 31, g = lane >> 5;
  const int row  = blockIdx.x >> 8;          // 256 blocks per row
  const int jb   = blockIdx.x & 255;
  const int n0   = jb * SEG;
  const float* __restrict__ xrow = x + (size_t)row * T_LEN;

  // A fragments -> VGPRs (L2-hot, coalesced dwordx4)
  half8 A[NCH];
  const half8* __restrict__ wsA = (const half8*)(ws + NTAPS);
#pragma unroll
  for (int c = 0; c < NCH; ++c) A[c] = wsA[c * 64 + lane];

  // stage x as fp16: coalesced float4 load -> cvt once -> swizzled 8B ds_write
  _Float16* xh = (_Float16*)smem;
#pragma unroll
  for (int j = 0; j < 5; ++j) {
    const int q4 = tid + 256 * j;            // float4 index
    if (q4 < STG_Q4) {
      int gfi = n0 - HALO + 4 * q4;          // clamp left edge (tail re-fixes)
      gfi = gfi < 0 ? 0 : gfi;
      const float4 f = *(const float4*)(xrow + gfi);
      const fp16x2 a = __builtin_amdgcn_cvt_pkrtz(f.x, f.y);
      const fp16x2 b = __builtin_amdgcn_cvt_pkrtz(f.z, f.w);
      uint2 w;
      w.x = __builtin_bit_cast(unsigned, a);
      w.y = __builtin_bit_cast(unsigned, b);
      const int c16 = q4 >> 1;               // 16B fp16 chunk
      *(uint2*)((char*)xh + swz16(c16) * 16 + (q4 & 1) * 8) = w;
    }
  }
  __syncthreads();

  // compute: 11 x { 1 ds_read_b128 + 1 MFMA }
  const int qb = wid * 128 + 4 * p + g;      // fp16-chunk base for this lane
  f32x16 acc = {};
#pragma unroll
  for (int c = 0; c < NCH; ++c) {
    const half8 B = *(const half8*)((char*)xh + swz16(qb + 2 * c) * 16);
    acc = __builtin_amdgcn_mfma_f32_32x32x16_f16(A[c], B, acc, 0, 0, 0);
  }
  __syncthreads();                           // all x-reads done before overwrite

  // epilogue: per-wave [pc][m] pad-36 transpose, all b128, then coalesced stores
  float* ebuf = (float*)smem + wid * EPI_F32;
#pragma unroll
  for (int k = 0; k < 4; ++k) {              // quad r=4k..4k+3: m = 8k+4g+j, col p
    float4 v;
    v.x = acc[4 * k];     v.y = acc[4 * k + 1];
    v.z = acc[4 * k + 2]; v.w = acc[4 * k + 3];
    *(float4*)(ebuf + p * 36 + 8 * k + 4 * g) = v;
  }
  // wave-private region: compiler orders ds_read after ds_write via lgkmcnt
  float* __restrict__ obase = out + (size_t)row * T_LEN + n0 + wid * 1024;
#pragma unroll
  for (int pp = 0; pp < 4; ++pp) {
    const int o  = 4 * lane + 256 * pp;      // outputs o..o+3 of this wave
    const int m0 = o & 31, pc = o >> 5;
    const float4 v = *(const float4*)(ebuf + pc * 36 + m0);
    *(float4*)(obase + o) = v;
  }

  // merged exact fp32 tail: first block of each row rewrites n in [0,254)
  if (jb == 0) {
    __syncthreads();                         // drain this block's main stores
    const float* __restrict__ h = ws;
    if (tid < 254) {
      float a = 0.f;
      if (tid < 127) {                       // circular wraparound region
        for (int k = tid + 1; k < NTAPS; ++k)
          a += h[k] * xrow[T_LEN + tid - k];
      } else {                               // causal with zero left-pad
        for (int k = 0; k <= tid - 127; ++k)
          a += h[k] * xrow[tid - 127 - k];
      }
      out[(size_t)row * T_LEN + tid] = a;
    }
  }
}

extern "C" void kernel_launch(void* const* d_in, const int* in_sizes, int n_in,
                              void* d_out, int out_size, void* d_ws, size_t ws_size,
                              hipStream_t stream) {
  const float* x      = (const float*)d_in[0];
  const float* w_real = (const float*)d_in[1];
  const float* w_imag = (const float*)d_in[2];
  const float* log_dt = (const float*)d_in[3];
  const float* C_real = (const float*)d_in[4];
  const float* C_imag = (const float*)d_in[5];
  const float* B_real = (const float*)d_in[6];
  const float* B_imag = (const float*)d_in[7];
  const float* Dp     = (const float*)d_in[8];
  float* out = (float*)d_out;
  float* ws  = (float*)d_ws;   // 128 f32 h + NCH*64*8 fp16 A-frags = 11.8 KB

  ssm_taps<<<1, NTAPS, 0, stream>>>(w_real, w_imag, log_dt,
                                    C_real, C_imag, B_real, B_imag, Dp, ws);
  ssm_conv<<<NROWS * SEGS_PER_ROW, BLOCK, 0, stream>>>(x, ws, out);
}